// Round 7
// baseline (92.130 us; speedup 1.0000x reference)
//
#include <hip/hip_runtime.h>

#define B_ 8
#define C_ 256
#define N_ 4096
#define CK 32
#define CG 128
#define M_ 1024

typedef __attribute__((ext_vector_type(8))) short bf16x8;
typedef __attribute__((ext_vector_type(4))) float f32x4;

__device__ __forceinline__ short f2bf(float f) {
  union { float f; unsigned u; } v; v.f = f;
  unsigned r = (v.u + 0x7FFF + ((v.u >> 16) & 1)) >> 16;  // RNE
  return (short)r;
}
__device__ __forceinline__ int packbf2(float a, float b) {
  return (f2bf(a) & 0xFFFF) | (f2bf(b) << 16);
}
__device__ __forceinline__ int cvtpk(float lo, float hi) {
  int r;
  asm("v_cvt_pk_bf16_f32 %0, %1, %2" : "=v"(r) : "v"(lo), "v"(hi));
  return r;
}

// ---------------- weight pre-convert: f32 -> bf16, once per launch
__global__ __launch_bounds__(256) void prep_kernel(const float* __restrict__ wt,
                                                   const float* __restrict__ wp,
                                                   const float* __restrict__ wg,
                                                   const float* __restrict__ wo,
                                                   short* __restrict__ wcat,
                                                   short* __restrict__ wo_bf) {
  int i = (blockIdx.x * 256 + threadIdx.x) * 4;
  const float* src;
  short* dst;
  int off;
  if (i < 8192)        { src = wt; dst = wcat;         off = i; }
  else if (i < 16384)  { src = wp; dst = wcat + 8192;  off = i - 8192; }
  else if (i < 49152)  { src = wg; dst = wcat + 16384; off = i - 16384; }
  else                 { src = wo; dst = wo_bf;        off = i - 49152; }
  float4 v = *(const float4*)(src + off);
  int2 p;
  p.x = packbf2(v.x, v.y);
  p.y = packbf2(v.z, v.w);
  *(int2*)(dst + off) = p;
}

// ---------------- fused projection: theta (unpooled) + phi/g (2x2 maxpooled)
__global__ __launch_bounds__(512) void proj_kernel(const float* __restrict__ x,
                                                   const short* __restrict__ wcat,
                                                   short* __restrict__ theta_t,
                                                   short* __restrict__ phi_t,
                                                   short* __restrict__ g_bf) {
  __shared__ __align__(16) short w_s[192 * 256];  // 96 KB, 16B-group swizzle g^(o&7)
  __shared__ __align__(16) short x_s[64 * 256];   // 32 KB, 16B-group swizzle g^(nl&7)
  int tid = threadIdx.x;
  int bx = blockIdx.x, b = blockIdx.y;
  int t = bx >> 1, half = bx & 1;

#pragma unroll
  for (int rep = 0; rep < 12; ++rep) {
    int idx = rep * 512 + tid;
    int o = idx >> 5, gp = idx & 31;
    int4 v = *(const int4*)&wcat[o * 256 + gp * 8];
    *(int4*)&w_s[o * 256 + ((gp ^ (o & 7)) * 8)] = v;
  }
  {
    int l = tid & 63, cq = tid >> 6;
    int xoff = l >> 1, dy = l & 1;
    int n = t * 128 + dy * 64 + half * 32 + xoff;
    const float* xb = x + (size_t)b * C_ * N_ + n;
#pragma unroll
    for (int rep = 0; rep < 2; ++rep) {
      int ch = cq + rep * 8;
      int c0 = ch * 16;
      float f[16];
#pragma unroll
      for (int i = 0; i < 16; ++i) f[i] = xb[(size_t)(c0 + i) * N_];
      int4 pa, pb;
      pa.x = cvtpk(f[0], f[1]);   pa.y = cvtpk(f[2], f[3]);
      pa.z = cvtpk(f[4], f[5]);   pa.w = cvtpk(f[6], f[7]);
      pb.x = cvtpk(f[8], f[9]);   pb.y = cvtpk(f[10], f[11]);
      pb.z = cvtpk(f[12], f[13]); pb.w = cvtpk(f[14], f[15]);
      *(int4*)&x_s[l * 256 + (((2 * ch) ^ (l & 7)) * 8)] = pa;
      *(int4*)&x_s[l * 256 + (((2 * ch + 1) ^ (l & 7)) * 8)] = pb;
    }
  }
  __syncthreads();

  int lane = tid & 63, w = tid >> 6;
  int h = lane >> 4, q = lane & 15;
  int ns = w & 3, ow = w >> 2;
  f32x4 acc[6];
#pragma unroll
  for (int j = 0; j < 6; ++j) acc[j] = (f32x4){0.f, 0.f, 0.f, 0.f};

  int nl = 16 * ns + q;
#pragma unroll
  for (int ks = 0; ks < 8; ++ks) {
    bf16x8 bfr = *(const bf16x8*)&x_s[nl * 256 + (((4 * ks + h) ^ (nl & 7)) * 8)];
#pragma unroll
    for (int j = 0; j < 6; ++j) {
      int o = 16 * (6 * ow + j) + q;
      bf16x8 afr = *(const bf16x8*)&w_s[o * 256 + (((4 * ks + h) ^ (o & 7)) * 8)];
      acc[j] = __builtin_amdgcn_mfma_f32_16x16x32_bf16(afr, bfr, acc[j], 0, 0, 0);
    }
  }

  int xoff = nl >> 1, dy = nl & 1;
  int n = t * 128 + dy * 64 + half * 32 + xoff;
  int m = t * 32 + half * 16 + (nl >> 2);
#pragma unroll
  for (int j = 0; j < 6; ++j) {
    int ot = 6 * ow + j;
    if (ot < 2) {  // theta, unpooled
      int2 pp;
      pp.x = cvtpk(acc[j][0], acc[j][1]);
      pp.y = cvtpk(acc[j][2], acc[j][3]);
      *(int2*)&theta_t[((size_t)b * N_ + n) * CK + ot * 16 + 4 * h] = pp;
    } else {  // pooled
      float v[4];
#pragma unroll
      for (int r = 0; r < 4; ++r) {
        float vv = acc[j][r];
        vv = fmaxf(vv, __shfl_xor(vv, 1));
        vv = fmaxf(vv, __shfl_xor(vv, 2));
        v[r] = vv;
      }
      if ((nl & 3) == 0) {
        if (ot < 4) {  // phi
          int2 pp;
          pp.x = cvtpk(v[0], v[1]);
          pp.y = cvtpk(v[2], v[3]);
          *(int2*)&phi_t[((size_t)b * M_ + m) * CK + (ot - 2) * 16 + 4 * h] = pp;
        } else {  // g
#pragma unroll
          for (int r = 0; r < 4; ++r) {
            int oc = (ot - 4) * 16 + 4 * h + r;
            g_bf[((size_t)b * CG + oc) * M_ + m] = f2bf(v[r]);
          }
        }
      }
    }
  }
}

// ---------------- flash attention, KVBLK=128, c-slice PV
// Wave w: QK+softmax for n-slice w (cols 16w..16w+15); PV for c-slice w
// (rows 32w..32w+31) over ALL 64 n. P and per-column rescale factors are
// shared through LDS. LDS row strides chosen so all b128 reads are 2-way
// bank-aliased (free): 136 shorts = 68 dw == 4 (mod 32); 40 shorts = 20 dw.
__global__ __launch_bounds__(256) void attn_kernel(const short* __restrict__ theta_t,
                                                   const short* __restrict__ phi_t,
                                                   const short* __restrict__ g_bf,
                                                   short* __restrict__ o_t) {
  __shared__ __align__(16) short phi_s[128 * 40];  // [m][c]   10.2 KB
  __shared__ __align__(16) short g_s[128 * 136];   // [c][m]   34.8 KB
  __shared__ __align__(16) short p_s[64 * 136];    // [n][m]   17.4 KB (shared)
  __shared__ float f_s[64];                        // per-col rescale / S

  int tid = threadIdx.x;
  int lane = tid & 63, w = tid >> 6;
  int h = lane >> 4, q = lane & 15;
  int b = blockIdx.y, n0 = blockIdx.x * 64;

  bf16x8 qfrag = *(const bf16x8*)&theta_t[((size_t)b * N_ + n0 + 16 * w + q) * CK + 8 * h];

  f32x4 Oacc[2][4];
#pragma unroll
  for (int ct = 0; ct < 2; ++ct)
#pragma unroll
    for (int nt = 0; nt < 4; ++nt) Oacc[ct][nt] = (f32x4){0.f, 0.f, 0.f, 0.f};
  float Mx = -INFINITY, S = 0.f;
  const f32x4 zero4 = {0.f, 0.f, 0.f, 0.f};

  // prologue: stage tile 0 (m = 0..127)
#pragma unroll
  for (int rep = 0; rep < 2; ++rep) {
    int idx = rep * 256 + tid, m = idx >> 2, cp = idx & 3;
    int4 v = *(const int4*)&phi_t[((size_t)b * M_ + m) * CK + 8 * cp];
    *(int4*)&phi_s[m * 40 + 8 * cp] = v;
  }
#pragma unroll
  for (int rep = 0; rep < 8; ++rep) {
    int idx = rep * 256 + tid, c = idx >> 4, mc = idx & 15;
    int4 v = *(const int4*)&g_bf[((size_t)b * CG + c) * M_ + 8 * mc];
    *(int4*)&g_s[c * 136 + 8 * mc] = v;
  }
  __syncthreads();

  for (int it = 0; it < 8; ++it) {
    // async-issue next tile's global loads (written to LDS after B2)
    int4 rphi[2], rg[8];
    if (it < 7) {
      int m0n = (it + 1) * 128;
#pragma unroll
      for (int rep = 0; rep < 2; ++rep) {
        int idx = rep * 256 + tid, m = idx >> 2, cp = idx & 3;
        rphi[rep] = *(const int4*)&phi_t[((size_t)b * M_ + m0n + m) * CK + 8 * cp];
      }
#pragma unroll
      for (int rep = 0; rep < 8; ++rep) {
        int idx = rep * 256 + tid, c = idx >> 4, mc = idx & 15;
        rg[rep] = *(const int4*)&g_bf[((size_t)b * CG + c) * M_ + m0n + 8 * mc];
      }
    }

    // QK^T for own n-slice: P^T[m=16mt+4h+r][n=16w+q]
    f32x4 pt[8];
#pragma unroll
    for (int mt = 0; mt < 8; ++mt) {
      bf16x8 af = *(const bf16x8*)&phi_s[(16 * mt + q) * 40 + 8 * h];
      pt[mt] = __builtin_amdgcn_mfma_f32_16x16x32_bf16(af, qfrag, zero4, 0, 0, 0);
    }

    // online softmax (own columns), defer-max THR=8
    float pm = pt[0][0];
#pragma unroll
    for (int mt = 0; mt < 8; ++mt)
#pragma unroll
      for (int r = 0; r < 4; ++r) pm = fmaxf(pm, pt[mt][r]);
    pm = fmaxf(pm, __shfl_xor(pm, 16));
    pm = fmaxf(pm, __shfl_xor(pm, 32));
    float fsc = 1.f;
    if (!__all(pm - Mx <= 8.f)) {
      float Mn = fmaxf(Mx, pm);
      fsc = __expf(Mx - Mn);
      S *= fsc;
      Mx = Mn;
    }
    float ps = 0.f;
#pragma unroll
    for (int mt = 0; mt < 8; ++mt) {
      float e0 = __expf(pt[mt][0] - Mx);
      float e1 = __expf(pt[mt][1] - Mx);
      float e2 = __expf(pt[mt][2] - Mx);
      float e3 = __expf(pt[mt][3] - Mx);
      ps += (e0 + e1) + (e2 + e3);
      int2 pk;
      pk.x = cvtpk(e0, e1);
      pk.y = cvtpk(e2, e3);
      *(int2*)&p_s[(16 * w + q) * 136 + 16 * mt + 4 * h] = pk;
    }
    ps += __shfl_xor(ps, 16);
    ps += __shfl_xor(ps, 32);
    S += ps;
    if (h == 0) f_s[16 * w + q] = fsc;
    __syncthreads();  // B1: p_s/f_s visible to all waves

    // rescale own O c-slice per COLUMN (factor from each column's owner wave)
    float ff[4];
#pragma unroll
    for (int nt = 0; nt < 4; ++nt) ff[nt] = f_s[16 * nt + q];
#pragma unroll
    for (int ct = 0; ct < 2; ++ct)
#pragma unroll
      for (int nt = 0; nt < 4; ++nt) Oacc[ct][nt] *= ff[nt];

    // PV: O^T[c-slice][all n] += V^T * P^T
#pragma unroll
    for (int kp = 0; kp < 4; ++kp) {
      bf16x8 pf[4];
#pragma unroll
      for (int nt = 0; nt < 4; ++nt)
        pf[nt] = *(const bf16x8*)&p_s[(16 * nt + q) * 136 + 32 * kp + 8 * h];
#pragma unroll
      for (int ct = 0; ct < 2; ++ct) {
        bf16x8 vf = *(const bf16x8*)&g_s[(32 * w + 16 * ct + q) * 136 + 32 * kp + 8 * h];
#pragma unroll
        for (int nt = 0; nt < 4; ++nt)
          Oacc[ct][nt] = __builtin_amdgcn_mfma_f32_16x16x32_bf16(vf, pf[nt], Oacc[ct][nt], 0, 0, 0);
      }
    }
    __syncthreads();  // B2: all LDS reads of this tile done

    if (it < 7) {
#pragma unroll
      for (int rep = 0; rep < 2; ++rep) {
        int idx = rep * 256 + tid, m = idx >> 2, cp = idx & 3;
        *(int4*)&phi_s[m * 40 + 8 * cp] = rphi[rep];
      }
#pragma unroll
      for (int rep = 0; rep < 8; ++rep) {
        int idx = rep * 256 + tid, c = idx >> 4, mc = idx & 15;
        *(int4*)&g_s[c * 136 + 8 * mc] = rg[rep];
      }
      __syncthreads();  // B3: next tile staged
    }
  }

  // epilogue: broadcast S per column, normalize, write o_t[b][n][c]
  if (h == 0) f_s[16 * w + q] = S;
  __syncthreads();
  float rs[4];
#pragma unroll
  for (int nt = 0; nt < 4; ++nt) rs[nt] = 1.f / f_s[16 * nt + q];
#pragma unroll
  for (int ct = 0; ct < 2; ++ct)
#pragma unroll
    for (int nt = 0; nt < 4; ++nt) {
      int2 pp;
      pp.x = cvtpk(Oacc[ct][nt][0] * rs[nt], Oacc[ct][nt][1] * rs[nt]);
      pp.y = cvtpk(Oacc[ct][nt][2] * rs[nt], Oacc[ct][nt][3] * rs[nt]);
      *(int2*)&o_t[((size_t)b * N_ + n0 + 16 * nt + q) * CG + 32 * w + 16 * ct + 4 * h] = pp;
    }
}

// ---------------- out projection + residual via bf16 MFMA (256 o x 64 n tile)
__global__ __launch_bounds__(512) void outproj_kernel(const short* __restrict__ o_t,
                                                      const short* __restrict__ wo_bf,
                                                      const float* __restrict__ x,
                                                      const float* __restrict__ gamma,
                                                      float* __restrict__ out) {
  __shared__ __align__(16) short wo_s[256 * 128];  // 64 KB, swizzle g^(o&7)
  __shared__ __align__(16) short ot_s[64 * 128];   // 16 KB, swizzle g^(n&7)
  int tid = threadIdx.x;
  int b = blockIdx.y, n0 = blockIdx.x * 64;

#pragma unroll
  for (int rep = 0; rep < 8; ++rep) {  // stage wo (bf16): [256 o][128 c]
    int idx = rep * 512 + tid;
    int o = idx >> 4, gp = idx & 15;
    int4 v = *(const int4*)&wo_bf[o * 128 + gp * 8];
    *(int4*)&wo_s[o * 128 + ((gp ^ (o & 7)) * 8)] = v;
  }
#pragma unroll
  for (int rep = 0; rep < 2; ++rep) {  // stage o_t tile: [64 n][128 c]
    int idx = rep * 512 + tid;
    int nl = idx >> 4, gp = idx & 15;
    int4 v = *(const int4*)&o_t[((size_t)b * N_ + n0 + nl) * CG + 8 * gp];
    *(int4*)&ot_s[nl * 128 + ((gp ^ (nl & 7)) * 8)] = v;
  }
  __syncthreads();

  int lane = tid & 63, w = tid >> 6;
  int h = lane >> 4, q = lane & 15;
  int ns = w & 3, oh = w >> 2;
  f32x4 acc[8];
#pragma unroll
  for (int j = 0; j < 8; ++j) acc[j] = (f32x4){0.f, 0.f, 0.f, 0.f};

  int nl = 16 * ns + q;
#pragma unroll
  for (int ks = 0; ks < 4; ++ks) {
    bf16x8 bfr = *(const bf16x8*)&ot_s[nl * 128 + (((4 * ks + h) ^ (nl & 7)) * 8)];
#pragma unroll
    for (int j = 0; j < 8; ++j) {
      int o = 128 * oh + 16 * j + q;
      bf16x8 afr = *(const bf16x8*)&wo_s[o * 128 + (((4 * ks + h) ^ (o & 7)) * 8)];
      acc[j] = __builtin_amdgcn_mfma_f32_16x16x32_bf16(afr, bfr, acc[j], 0, 0, 0);
    }
  }

  float gm = gamma[0];
  int n = n0 + 16 * ns + q;
#pragma unroll
  for (int j = 0; j < 8; ++j)
#pragma unroll
    for (int r = 0; r < 4; ++r) {
      int o = 128 * oh + 16 * j + 4 * h + r;
      size_t idx = ((size_t)b * C_ + o) * N_ + n;
      out[idx] = gm * acc[j][r] + x[idx];
    }
}

extern "C" void kernel_launch(void* const* d_in, const int* in_sizes, int n_in,
                              void* d_out, int out_size, void* d_ws, size_t ws_size,
                              hipStream_t stream) {
  const float* x = (const float*)d_in[0];
  const float* wt = (const float*)d_in[1];
  const float* wp = (const float*)d_in[2];
  const float* wg = (const float*)d_in[3];
  const float* wo = (const float*)d_in[4];
  const float* gamma = (const float*)d_in[5];
  float* out = (float*)d_out;

  short* theta_t = (short*)d_ws;                       // 8*4096*32
  short* phi_t = theta_t + (size_t)B_ * N_ * CK;       // 8*1024*32
  short* g_bf = phi_t + (size_t)B_ * M_ * CK;          // 8*128*1024
  short* o_t = g_bf + (size_t)B_ * CG * M_;            // 8*4096*128
  short* wcat = o_t + (size_t)B_ * N_ * CG;            // 192*256
  short* wo_bf = wcat + 192 * 256;                     // 256*128

  prep_kernel<<<dim3(80), 256, 0, stream>>>(wt, wp, wg, wo, wcat, wo_bf);
  proj_kernel<<<dim3(64, 8), 512, 0, stream>>>(x, wcat, theta_t, phi_t, g_bf);
  attn_kernel<<<dim3(64, 8), 256, 0, stream>>>(theta_t, phi_t, g_bf, o_t);
  outproj_kernel<<<dim3(64, 8), 512, 0, stream>>>(o_t, wo_bf, x, gamma, out);
}

// Round 8
// 63.036 us; speedup vs baseline: 1.4616x; 1.4616x over previous
//
#include <hip/hip_runtime.h>

#define B_ 8
#define C_ 256
#define N_ 4096
#define CK 32
#define CG 128
#define M_ 1024

typedef __attribute__((ext_vector_type(8))) short bf16x8;
typedef __attribute__((ext_vector_type(4))) float f32x4;

__device__ __forceinline__ short f2bf(float f) {
  union { float f; unsigned u; } v; v.f = f;
  unsigned r = (v.u + 0x7FFF + ((v.u >> 16) & 1)) >> 16;  // RNE
  return (short)r;
}
__device__ __forceinline__ int packbf2(float a, float b) {
  return (f2bf(a) & 0xFFFF) | (f2bf(b) << 16);
}
__device__ __forceinline__ int cvtpk(float lo, float hi) {
  int r;
  asm("v_cvt_pk_bf16_f32 %0, %1, %2" : "=v"(r) : "v"(lo), "v"(hi));
  return r;
}

// ---------------- weight pre-convert: f32 -> bf16, once per launch
__global__ __launch_bounds__(256) void prep_kernel(const float* __restrict__ wt,
                                                   const float* __restrict__ wp,
                                                   const float* __restrict__ wg,
                                                   const float* __restrict__ wo,
                                                   short* __restrict__ wcat,
                                                   short* __restrict__ wo_bf) {
  int i = (blockIdx.x * 256 + threadIdx.x) * 4;
  const float* src;
  short* dst;
  int off;
  if (i < 8192)        { src = wt; dst = wcat;         off = i; }
  else if (i < 16384)  { src = wp; dst = wcat + 8192;  off = i - 8192; }
  else if (i < 49152)  { src = wg; dst = wcat + 16384; off = i - 16384; }
  else                 { src = wo; dst = wo_bf;        off = i - 49152; }
  float4 v = *(const float4*)(src + off);
  int2 p;
  p.x = packbf2(v.x, v.y);
  p.y = packbf2(v.z, v.w);
  *(int2*)(dst + off) = p;
}

// ---------------- fused projection: theta (unpooled) + phi/g (2x2 maxpooled)
__global__ __launch_bounds__(512) void proj_kernel(const float* __restrict__ x,
                                                   const short* __restrict__ wcat,
                                                   short* __restrict__ theta_t,
                                                   short* __restrict__ phi_t,
                                                   short* __restrict__ g_bf) {
  __shared__ __align__(16) short w_s[192 * 256];  // 96 KB, 16B-group swizzle g^(o&7)
  __shared__ __align__(16) short x_s[64 * 256];   // 32 KB, 16B-group swizzle g^(nl&7)
  int tid = threadIdx.x;
  int bx = blockIdx.x, b = blockIdx.y;
  int t = bx >> 1, half = bx & 1;

#pragma unroll
  for (int rep = 0; rep < 12; ++rep) {
    int idx = rep * 512 + tid;
    int o = idx >> 5, gp = idx & 31;
    int4 v = *(const int4*)&wcat[o * 256 + gp * 8];
    *(int4*)&w_s[o * 256 + ((gp ^ (o & 7)) * 8)] = v;
  }
  {
    int l = tid & 63, cq = tid >> 6;
    int xoff = l >> 1, dy = l & 1;
    int n = t * 128 + dy * 64 + half * 32 + xoff;
    const float* xb = x + (size_t)b * C_ * N_ + n;
#pragma unroll
    for (int rep = 0; rep < 2; ++rep) {
      int ch = cq + rep * 8;
      int c0 = ch * 16;
      float f[16];
#pragma unroll
      for (int i = 0; i < 16; ++i) f[i] = xb[(size_t)(c0 + i) * N_];
      int4 pa, pb;
      pa.x = cvtpk(f[0], f[1]);   pa.y = cvtpk(f[2], f[3]);
      pa.z = cvtpk(f[4], f[5]);   pa.w = cvtpk(f[6], f[7]);
      pb.x = cvtpk(f[8], f[9]);   pb.y = cvtpk(f[10], f[11]);
      pb.z = cvtpk(f[12], f[13]); pb.w = cvtpk(f[14], f[15]);
      *(int4*)&x_s[l * 256 + (((2 * ch) ^ (l & 7)) * 8)] = pa;
      *(int4*)&x_s[l * 256 + (((2 * ch + 1) ^ (l & 7)) * 8)] = pb;
    }
  }
  __syncthreads();

  int lane = tid & 63, w = tid >> 6;
  int h = lane >> 4, q = lane & 15;
  int ns = w & 3, ow = w >> 2;
  f32x4 acc[6];
#pragma unroll
  for (int j = 0; j < 6; ++j) acc[j] = (f32x4){0.f, 0.f, 0.f, 0.f};

  int nl = 16 * ns + q;
#pragma unroll
  for (int ks = 0; ks < 8; ++ks) {
    bf16x8 bfr = *(const bf16x8*)&x_s[nl * 256 + (((4 * ks + h) ^ (nl & 7)) * 8)];
#pragma unroll
    for (int j = 0; j < 6; ++j) {
      int o = 16 * (6 * ow + j) + q;
      bf16x8 afr = *(const bf16x8*)&w_s[o * 256 + (((4 * ks + h) ^ (o & 7)) * 8)];
      acc[j] = __builtin_amdgcn_mfma_f32_16x16x32_bf16(afr, bfr, acc[j], 0, 0, 0);
    }
  }

  int xoff = nl >> 1, dy = nl & 1;
  int n = t * 128 + dy * 64 + half * 32 + xoff;
  int m = t * 32 + half * 16 + (nl >> 2);
#pragma unroll
  for (int j = 0; j < 6; ++j) {
    int ot = 6 * ow + j;
    if (ot < 2) {  // theta, unpooled
      int2 pp;
      pp.x = cvtpk(acc[j][0], acc[j][1]);
      pp.y = cvtpk(acc[j][2], acc[j][3]);
      *(int2*)&theta_t[((size_t)b * N_ + n) * CK + ot * 16 + 4 * h] = pp;
    } else {  // pooled
      float v[4];
#pragma unroll
      for (int r = 0; r < 4; ++r) {
        float vv = acc[j][r];
        vv = fmaxf(vv, __shfl_xor(vv, 1));
        vv = fmaxf(vv, __shfl_xor(vv, 2));
        v[r] = vv;
      }
      if ((nl & 3) == 0) {
        if (ot < 4) {  // phi
          int2 pp;
          pp.x = cvtpk(v[0], v[1]);
          pp.y = cvtpk(v[2], v[3]);
          *(int2*)&phi_t[((size_t)b * M_ + m) * CK + (ot - 2) * 16 + 4 * h] = pp;
        } else {  // g
#pragma unroll
          for (int r = 0; r < 4; ++r) {
            int oc = (ot - 4) * 16 + 4 * h + r;
            g_bf[((size_t)b * CG + oc) * M_ + m] = f2bf(v[r]);
          }
        }
      }
    }
  }
}

// ---------------- flash attention: private-P waves, double-buffered LDS,
// 1 barrier/iter, coalesced o_t epilogue, XCD-local batch assignment.
// Block: 128 queries (8 waves x 16 n), 16 m-tiles of 64.
__global__ __launch_bounds__(512, 2) void attn_kernel(const short* __restrict__ theta_t,
                                                      const short* __restrict__ phi_t,
                                                      const short* __restrict__ g_bf,
                                                      short* __restrict__ o_t) {
  __shared__ __align__(16) short phi_s[2][64 * 40];   // [m][c] stride 40
  __shared__ __align__(16) short g_s[2][128 * 72];    // [c][m] stride 72
  __shared__ __align__(16) short p_s[8][16 * 72];     // per-wave [q][m]

  int tid = threadIdx.x;
  int lane = tid & 63, w = tid >> 6;
  int h = lane >> 4, q = lane & 15;
  int bid = blockIdx.x;
  int b = bid & 7, n0 = (bid >> 3) * 128;  // same-b blocks land on same XCD
  int n = n0 + 16 * w + q;

  bf16x8 qfrag = *(const bf16x8*)&theta_t[((size_t)b * N_ + n) * CK + 8 * h];

  f32x4 Oacc[8];
#pragma unroll
  for (int ct = 0; ct < 8; ++ct) Oacc[ct] = (f32x4){0.f, 0.f, 0.f, 0.f};
  float Mx = -INFINITY, S = 0.f;
  const f32x4 zero4 = {0.f, 0.f, 0.f, 0.f};

  // staging coords: phi (threads 0..255), g (2 int4 per thread)
  int pm_ = tid >> 2, pc_ = tid & 3;
  int gc0 = tid >> 3, gm0 = tid & 7;
  int gc1 = (512 + tid) >> 3, gm1 = tid & 7;

  // prologue: stage tile 0 into buffer 0
  if (tid < 256)
    *(int4*)&phi_s[0][pm_ * 40 + 8 * pc_] =
        *(const int4*)&phi_t[((size_t)b * M_ + pm_) * CK + 8 * pc_];
  *(int4*)&g_s[0][gc0 * 72 + 8 * gm0] =
      *(const int4*)&g_bf[((size_t)b * CG + gc0) * M_ + 8 * gm0];
  *(int4*)&g_s[0][gc1 * 72 + 8 * gm1] =
      *(const int4*)&g_bf[((size_t)b * CG + gc1) * M_ + 8 * gm1];
  __syncthreads();

  for (int it = 0; it < 16; ++it) {
    int cur = it & 1;
    // issue next tile's global loads early (T14: latency hides under compute)
    int4 rphi, rg0, rg1;
    if (it < 15) {
      int m0n = (it + 1) * 64;
      if (tid < 256)
        rphi = *(const int4*)&phi_t[((size_t)b * M_ + m0n + pm_) * CK + 8 * pc_];
      rg0 = *(const int4*)&g_bf[((size_t)b * CG + gc0) * M_ + m0n + 8 * gm0];
      rg1 = *(const int4*)&g_bf[((size_t)b * CG + gc1) * M_ + m0n + 8 * gm1];
    }

    // QK^T: P^T[m][n], own 16-n slice
    f32x4 pt[4];
#pragma unroll
    for (int mt = 0; mt < 4; ++mt) {
      bf16x8 af = *(const bf16x8*)&phi_s[cur][(16 * mt + q) * 40 + 8 * h];
      pt[mt] = __builtin_amdgcn_mfma_f32_16x16x32_bf16(af, qfrag, zero4, 0, 0, 0);
    }

    // online softmax, defer-max THR=8
    float pm = pt[0][0];
#pragma unroll
    for (int mt = 0; mt < 4; ++mt)
#pragma unroll
      for (int r = 0; r < 4; ++r) pm = fmaxf(pm, pt[mt][r]);
    pm = fmaxf(pm, __shfl_xor(pm, 16));
    pm = fmaxf(pm, __shfl_xor(pm, 32));
    if (!__all(pm - Mx <= 8.f)) {
      float Mn = fmaxf(Mx, pm);
      float fsc = __expf(Mx - Mn);
      S *= fsc;
#pragma unroll
      for (int ct = 0; ct < 8; ++ct) Oacc[ct] *= fsc;
      Mx = Mn;
    }
    float ps = 0.f;
#pragma unroll
    for (int mt = 0; mt < 4; ++mt) {
      float e0 = __expf(pt[mt][0] - Mx);
      float e1 = __expf(pt[mt][1] - Mx);
      float e2 = __expf(pt[mt][2] - Mx);
      float e3 = __expf(pt[mt][3] - Mx);
      ps += (e0 + e1) + (e2 + e3);
      int2 pk;
      pk.x = cvtpk(e0, e1);
      pk.y = cvtpk(e2, e3);
      *(int2*)&p_s[w][q * 72 + 16 * mt + 4 * h] = pk;
    }
    ps += __shfl_xor(ps, 16);
    ps += __shfl_xor(ps, 32);
    S += ps;

    // PV: O^T[all 128 c][own 16 n]
    __builtin_amdgcn_s_setprio(1);
#pragma unroll
    for (int kp = 0; kp < 2; ++kp) {
      bf16x8 pf = *(const bf16x8*)&p_s[w][q * 72 + 32 * kp + 8 * h];
#pragma unroll
      for (int ct = 0; ct < 8; ++ct) {
        bf16x8 vf = *(const bf16x8*)&g_s[cur][(16 * ct + q) * 72 + 32 * kp + 8 * h];
        Oacc[ct] = __builtin_amdgcn_mfma_f32_16x16x32_bf16(vf, pf, Oacc[ct], 0, 0, 0);
      }
    }
    __builtin_amdgcn_s_setprio(0);

    // write next tile into the spare buffer (no reader conflict), then barrier
    if (it < 15) {
      int nxt = cur ^ 1;
      if (tid < 256) *(int4*)&phi_s[nxt][pm_ * 40 + 8 * pc_] = rphi;
      *(int4*)&g_s[nxt][gc0 * 72 + 8 * gm0] = rg0;
      *(int4*)&g_s[nxt][gc1 * 72 + 8 * gm1] = rg1;
    }
    __syncthreads();
  }

  // epilogue: normalize, stage O through LDS (reuse g_s), coalesced o_t write
  short* ot_s = &g_s[0][0];  // 128 rows x 136 stride = 17408 sh <= 18432 sh
  float rS = 1.f / S;
  int nloc = 16 * w + q;
#pragma unroll
  for (int ct = 0; ct < 8; ++ct) {
    int2 pp;
    pp.x = cvtpk(Oacc[ct][0] * rS, Oacc[ct][1] * rS);
    pp.y = cvtpk(Oacc[ct][2] * rS, Oacc[ct][3] * rS);
    *(int2*)&ot_s[nloc * 136 + 16 * ct + 4 * h] = pp;
  }
  __syncthreads();
#pragma unroll
  for (int rep = 0; rep < 4; ++rep) {
    int idx = rep * 512 + tid;
    int row = idx >> 4, col = idx & 15;
    int4 v = *(const int4*)&ot_s[row * 136 + col * 8];
    *(int4*)&o_t[((size_t)b * N_ + n0 + row) * CG + col * 8] = v;
  }
}

// ---------------- out projection + residual via bf16 MFMA (256 o x 64 n tile)
__global__ __launch_bounds__(512) void outproj_kernel(const short* __restrict__ o_t,
                                                      const short* __restrict__ wo_bf,
                                                      const float* __restrict__ x,
                                                      const float* __restrict__ gamma,
                                                      float* __restrict__ out) {
  __shared__ __align__(16) short wo_s[256 * 128];  // 64 KB, swizzle g^(o&7)
  __shared__ __align__(16) short ot_s[64 * 128];   // 16 KB, swizzle g^(n&7)
  int tid = threadIdx.x;
  int b = blockIdx.y, n0 = blockIdx.x * 64;

#pragma unroll
  for (int rep = 0; rep < 8; ++rep) {  // stage wo (bf16): [256 o][128 c]
    int idx = rep * 512 + tid;
    int o = idx >> 4, gp = idx & 15;
    int4 v = *(const int4*)&wo_bf[o * 128 + gp * 8];
    *(int4*)&wo_s[o * 128 + ((gp ^ (o & 7)) * 8)] = v;
  }
#pragma unroll
  for (int rep = 0; rep < 2; ++rep) {  // stage o_t tile: [64 n][128 c]
    int idx = rep * 512 + tid;
    int nl = idx >> 4, gp = idx & 15;
    int4 v = *(const int4*)&o_t[((size_t)b * N_ + n0 + nl) * CG + 8 * gp];
    *(int4*)&ot_s[nl * 128 + ((gp ^ (nl & 7)) * 8)] = v;
  }
  __syncthreads();

  int lane = tid & 63, w = tid >> 6;
  int h = lane >> 4, q = lane & 15;
  int ns = w & 3, oh = w >> 2;
  f32x4 acc[8];
#pragma unroll
  for (int j = 0; j < 8; ++j) acc[j] = (f32x4){0.f, 0.f, 0.f, 0.f};

  int nl = 16 * ns + q;
#pragma unroll
  for (int ks = 0; ks < 4; ++ks) {
    bf16x8 bfr = *(const bf16x8*)&ot_s[nl * 128 + (((4 * ks + h) ^ (nl & 7)) * 8)];
#pragma unroll
    for (int j = 0; j < 8; ++j) {
      int o = 128 * oh + 16 * j + q;
      bf16x8 afr = *(const bf16x8*)&wo_s[o * 128 + (((4 * ks + h) ^ (o & 7)) * 8)];
      acc[j] = __builtin_amdgcn_mfma_f32_16x16x32_bf16(afr, bfr, acc[j], 0, 0, 0);
    }
  }

  float gm = gamma[0];
  int n = n0 + 16 * ns + q;
#pragma unroll
  for (int j = 0; j < 8; ++j)
#pragma unroll
    for (int r = 0; r < 4; ++r) {
      int o = 128 * oh + 16 * j + 4 * h + r;
      size_t idx = ((size_t)b * C_ + o) * N_ + n;
      out[idx] = gm * acc[j][r] + x[idx];
    }
}

extern "C" void kernel_launch(void* const* d_in, const int* in_sizes, int n_in,
                              void* d_out, int out_size, void* d_ws, size_t ws_size,
                              hipStream_t stream) {
  const float* x = (const float*)d_in[0];
  const float* wt = (const float*)d_in[1];
  const float* wp = (const float*)d_in[2];
  const float* wg = (const float*)d_in[3];
  const float* wo = (const float*)d_in[4];
  const float* gamma = (const float*)d_in[5];
  float* out = (float*)d_out;

  short* theta_t = (short*)d_ws;                       // 8*4096*32
  short* phi_t = theta_t + (size_t)B_ * N_ * CK;       // 8*1024*32
  short* g_bf = phi_t + (size_t)B_ * M_ * CK;          // 8*128*1024
  short* o_t = g_bf + (size_t)B_ * CG * M_;            // 8*4096*128
  short* wcat = o_t + (size_t)B_ * N_ * CG;            // 192*256
  short* wo_bf = wcat + 192 * 256;                     // 256*128

  prep_kernel<<<dim3(80), 256, 0, stream>>>(wt, wp, wg, wo, wcat, wo_bf);
  proj_kernel<<<dim3(64, 8), 512, 0, stream>>>(x, wcat, theta_t, phi_t, g_bf);
  attn_kernel<<<dim3(256), 512, 0, stream>>>(theta_t, phi_t, g_bf, o_t);
  outproj_kernel<<<dim3(64, 8), 512, 0, stream>>>(o_t, wo_bf, x, gamma, out);
}

// Round 9
// 59.074 us; speedup vs baseline: 1.5596x; 1.0671x over previous
//
#include <hip/hip_runtime.h>

#define B_ 8
#define C_ 256
#define N_ 4096
#define CK 32
#define CG 128
#define M_ 1024

typedef __attribute__((ext_vector_type(8))) short bf16x8;
typedef __attribute__((ext_vector_type(4))) float f32x4;

__device__ __forceinline__ short f2bf(float f) {
  union { float f; unsigned u; } v; v.f = f;
  unsigned r = (v.u + 0x7FFF + ((v.u >> 16) & 1)) >> 16;  // RNE
  return (short)r;
}
__device__ __forceinline__ int packbf2(float a, float b) {
  return (f2bf(a) & 0xFFFF) | (f2bf(b) << 16);
}
__device__ __forceinline__ int cvtpk(float lo, float hi) {
  int r;
  asm("v_cvt_pk_bf16_f32 %0, %1, %2" : "=v"(r) : "v"(lo), "v"(hi));
  return r;
}

// ---------------- weight pre-convert: f32 -> bf16, once per launch
__global__ __launch_bounds__(256) void prep_kernel(const float* __restrict__ wt,
                                                   const float* __restrict__ wp,
                                                   const float* __restrict__ wg,
                                                   const float* __restrict__ wo,
                                                   short* __restrict__ wcat,
                                                   short* __restrict__ wo_bf) {
  int i = (blockIdx.x * 256 + threadIdx.x) * 4;
  const float* src;
  short* dst;
  int off;
  if (i < 8192)        { src = wt; dst = wcat;         off = i; }
  else if (i < 16384)  { src = wp; dst = wcat + 8192;  off = i - 8192; }
  else if (i < 49152)  { src = wg; dst = wcat + 16384; off = i - 16384; }
  else                 { src = wo; dst = wo_bf;        off = i - 49152; }
  float4 v = *(const float4*)(src + off);
  int2 p;
  p.x = packbf2(v.x, v.y);
  p.y = packbf2(v.z, v.w);
  *(int2*)(dst + off) = p;
}

// ---------------- fused projection: theta (unpooled) + phi/g (2x2 maxpooled)
__global__ __launch_bounds__(512) void proj_kernel(const float* __restrict__ x,
                                                   const short* __restrict__ wcat,
                                                   short* __restrict__ theta_t,
                                                   short* __restrict__ phi_t,
                                                   short* __restrict__ g_bf) {
  __shared__ __align__(16) short w_s[192 * 256];  // 96 KB, 16B-group swizzle g^(o&7)
  __shared__ __align__(16) short x_s[64 * 256];   // 32 KB, 16B-group swizzle g^(nl&7)
  int tid = threadIdx.x;
  int bx = blockIdx.x, b = blockIdx.y;
  int t = bx >> 1, half = bx & 1;

#pragma unroll
  for (int rep = 0; rep < 12; ++rep) {
    int idx = rep * 512 + tid;
    int o = idx >> 5, gp = idx & 31;
    int4 v = *(const int4*)&wcat[o * 256 + gp * 8];
    *(int4*)&w_s[o * 256 + ((gp ^ (o & 7)) * 8)] = v;
  }
  {
    int l = tid & 63, cq = tid >> 6;
    int xoff = l >> 1, dy = l & 1;
    int n = t * 128 + dy * 64 + half * 32 + xoff;
    const float* xb = x + (size_t)b * C_ * N_ + n;
#pragma unroll
    for (int rep = 0; rep < 2; ++rep) {
      int ch = cq + rep * 8;
      int c0 = ch * 16;
      float f[16];
#pragma unroll
      for (int i = 0; i < 16; ++i) f[i] = xb[(size_t)(c0 + i) * N_];
      int4 pa, pb;
      pa.x = cvtpk(f[0], f[1]);   pa.y = cvtpk(f[2], f[3]);
      pa.z = cvtpk(f[4], f[5]);   pa.w = cvtpk(f[6], f[7]);
      pb.x = cvtpk(f[8], f[9]);   pb.y = cvtpk(f[10], f[11]);
      pb.z = cvtpk(f[12], f[13]); pb.w = cvtpk(f[14], f[15]);
      *(int4*)&x_s[l * 256 + (((2 * ch) ^ (l & 7)) * 8)] = pa;
      *(int4*)&x_s[l * 256 + (((2 * ch + 1) ^ (l & 7)) * 8)] = pb;
    }
  }
  __syncthreads();

  int lane = tid & 63, w = tid >> 6;
  int h = lane >> 4, q = lane & 15;
  int ns = w & 3, ow = w >> 2;
  f32x4 acc[6];
#pragma unroll
  for (int j = 0; j < 6; ++j) acc[j] = (f32x4){0.f, 0.f, 0.f, 0.f};

  int nl = 16 * ns + q;
#pragma unroll
  for (int ks = 0; ks < 8; ++ks) {
    bf16x8 bfr = *(const bf16x8*)&x_s[nl * 256 + (((4 * ks + h) ^ (nl & 7)) * 8)];
#pragma unroll
    for (int j = 0; j < 6; ++j) {
      int o = 16 * (6 * ow + j) + q;
      bf16x8 afr = *(const bf16x8*)&w_s[o * 256 + (((4 * ks + h) ^ (o & 7)) * 8)];
      acc[j] = __builtin_amdgcn_mfma_f32_16x16x32_bf16(afr, bfr, acc[j], 0, 0, 0);
    }
  }

  int xoff = nl >> 1, dy = nl & 1;
  int n = t * 128 + dy * 64 + half * 32 + xoff;
  int m = t * 32 + half * 16 + (nl >> 2);
#pragma unroll
  for (int j = 0; j < 6; ++j) {
    int ot = 6 * ow + j;
    if (ot < 2) {  // theta, unpooled
      int2 pp;
      pp.x = cvtpk(acc[j][0], acc[j][1]);
      pp.y = cvtpk(acc[j][2], acc[j][3]);
      *(int2*)&theta_t[((size_t)b * N_ + n) * CK + ot * 16 + 4 * h] = pp;
    } else {  // pooled
      float v[4];
#pragma unroll
      for (int r = 0; r < 4; ++r) {
        float vv = acc[j][r];
        vv = fmaxf(vv, __shfl_xor(vv, 1));
        vv = fmaxf(vv, __shfl_xor(vv, 2));
        v[r] = vv;
      }
      if ((nl & 3) == 0) {
        if (ot < 4) {  // phi
          int2 pp;
          pp.x = cvtpk(v[0], v[1]);
          pp.y = cvtpk(v[2], v[3]);
          *(int2*)&phi_t[((size_t)b * M_ + m) * CK + (ot - 2) * 16 + 4 * h] = pp;
        } else {  // g
#pragma unroll
          for (int r = 0; r < 4; ++r) {
            int oc = (ot - 4) * 16 + 4 * h + r;
            g_bf[((size_t)b * CG + oc) * M_ + m] = f2bf(v[r]);
          }
        }
      }
    }
  }
}

// ---------------- fused flash-attention + out-projection + residual
// Block: 128 queries (8 waves x 16 n), 16 m-tiles of 64. After the attention
// loop the normalized O tile ([128 n][128 c], bf16) stays in LDS and feeds the
// w_o MFMA directly; epilogue writes gamma*(w_o O) + x. No o_t round-trip.
// LDS: main loop phi(2x5120)+g(2x18432... see offsets below; epilogue reuses
// the same pool as ot_s[128*136] + wo_s[256*128] = 100,352 B total.
__global__ __launch_bounds__(512, 1) void attn_out_kernel(const short* __restrict__ theta_t,
                                                          const short* __restrict__ phi_t,
                                                          const short* __restrict__ g_bf,
                                                          const short* __restrict__ wo_bf,
                                                          const float* __restrict__ x,
                                                          const float* __restrict__ gamma,
                                                          float* __restrict__ out) {
  __shared__ __align__(16) short lds[50176];  // 100,352 B
  short* phi_s = lds;          // 2 x 2560 sh  ([m][c] stride 40)
  short* g_sA = lds + 5120;    // 2 x 9216 sh  ([c][m] stride 72)
  short* p_sb = lds + 23552;   // 8 x 1152 sh  (per-wave [q][m] stride 72)

  int tid = threadIdx.x;
  int lane = tid & 63, w = tid >> 6;
  int h = lane >> 4, q = lane & 15;
  int bid = blockIdx.x;
  int b = bid & 7, n0 = (bid >> 3) * 128;  // same-b blocks land on same XCD
  int n = n0 + 16 * w + q;
  float gm = gamma[0];

  bf16x8 qfrag = *(const bf16x8*)&theta_t[((size_t)b * N_ + n) * CK + 8 * h];

  f32x4 Oacc[8];
#pragma unroll
  for (int ct = 0; ct < 8; ++ct) Oacc[ct] = (f32x4){0.f, 0.f, 0.f, 0.f};
  float Mx = -INFINITY, S = 0.f;
  const f32x4 zero4 = {0.f, 0.f, 0.f, 0.f};

  // staging coords
  int pm_ = tid >> 2, pc_ = tid & 3;
  int gc0 = tid >> 3, gm0 = tid & 7;
  int gc1 = (512 + tid) >> 3, gm1 = tid & 7;
  short* p_sw = p_sb + w * 1152;

  // prologue: stage tile 0 into buffer 0
  if (tid < 256)
    *(int4*)&phi_s[pm_ * 40 + 8 * pc_] =
        *(const int4*)&phi_t[((size_t)b * M_ + pm_) * CK + 8 * pc_];
  *(int4*)&g_sA[gc0 * 72 + 8 * gm0] =
      *(const int4*)&g_bf[((size_t)b * CG + gc0) * M_ + 8 * gm0];
  *(int4*)&g_sA[gc1 * 72 + 8 * gm1] =
      *(const int4*)&g_bf[((size_t)b * CG + gc1) * M_ + 8 * gm1];
  __syncthreads();

  for (int it = 0; it < 16; ++it) {
    int cur = it & 1;
    short* phi_c = phi_s + cur * 2560;
    short* g_c = g_sA + cur * 9216;
    // issue next tile's global loads early (T14)
    int4 rphi, rg0, rg1;
    if (it < 15) {
      int m0n = (it + 1) * 64;
      if (tid < 256)
        rphi = *(const int4*)&phi_t[((size_t)b * M_ + m0n + pm_) * CK + 8 * pc_];
      rg0 = *(const int4*)&g_bf[((size_t)b * CG + gc0) * M_ + m0n + 8 * gm0];
      rg1 = *(const int4*)&g_bf[((size_t)b * CG + gc1) * M_ + m0n + 8 * gm1];
    }

    // QK^T: P^T[m][n], own 16-n slice
    f32x4 pt[4];
#pragma unroll
    for (int mt = 0; mt < 4; ++mt) {
      bf16x8 af = *(const bf16x8*)&phi_c[(16 * mt + q) * 40 + 8 * h];
      pt[mt] = __builtin_amdgcn_mfma_f32_16x16x32_bf16(af, qfrag, zero4, 0, 0, 0);
    }

    // online softmax, defer-max THR=8
    float pm = pt[0][0];
#pragma unroll
    for (int mt = 0; mt < 4; ++mt)
#pragma unroll
      for (int r = 0; r < 4; ++r) pm = fmaxf(pm, pt[mt][r]);
    pm = fmaxf(pm, __shfl_xor(pm, 16));
    pm = fmaxf(pm, __shfl_xor(pm, 32));
    if (!__all(pm - Mx <= 8.f)) {
      float Mn = fmaxf(Mx, pm);
      float fsc = __expf(Mx - Mn);
      S *= fsc;
#pragma unroll
      for (int ct = 0; ct < 8; ++ct) Oacc[ct] *= fsc;
      Mx = Mn;
    }
    float ps = 0.f;
#pragma unroll
    for (int mt = 0; mt < 4; ++mt) {
      float e0 = __expf(pt[mt][0] - Mx);
      float e1 = __expf(pt[mt][1] - Mx);
      float e2 = __expf(pt[mt][2] - Mx);
      float e3 = __expf(pt[mt][3] - Mx);
      ps += (e0 + e1) + (e2 + e3);
      int2 pk;
      pk.x = cvtpk(e0, e1);
      pk.y = cvtpk(e2, e3);
      *(int2*)&p_sw[q * 72 + 16 * mt + 4 * h] = pk;
    }
    ps += __shfl_xor(ps, 16);
    ps += __shfl_xor(ps, 32);
    S += ps;

    // PV: O^T[all 128 c][own 16 n]
    __builtin_amdgcn_s_setprio(1);
#pragma unroll
    for (int kp = 0; kp < 2; ++kp) {
      bf16x8 pf = *(const bf16x8*)&p_sw[q * 72 + 32 * kp + 8 * h];
#pragma unroll
      for (int ct = 0; ct < 8; ++ct) {
        bf16x8 vf = *(const bf16x8*)&g_c[(16 * ct + q) * 72 + 32 * kp + 8 * h];
        Oacc[ct] = __builtin_amdgcn_mfma_f32_16x16x32_bf16(vf, pf, Oacc[ct], 0, 0, 0);
      }
    }
    __builtin_amdgcn_s_setprio(0);

    // write next tile into the spare buffer, then one barrier
    if (it < 15) {
      int nxt = cur ^ 1;
      if (tid < 256) *(int4*)&phi_s[nxt * 2560 + pm_ * 40 + 8 * pc_] = rphi;
      *(int4*)&g_sA[nxt * 9216 + gc0 * 72 + 8 * gm0] = rg0;
      *(int4*)&g_sA[nxt * 9216 + gc1 * 72 + 8 * gm1] = rg1;
    }
    __syncthreads();
  }

  // ---- epilogue phase 1: normalized O -> ot_s[128 n][stride 136]; stage wo
  short* ot_s = lds;            // 17408 sh
  short* wo_s = lds + 17408;    // 32768 sh, swizzle g^(o&7)
  float rS = 1.f / S;
  int nloc = 16 * w + q;
#pragma unroll
  for (int ct = 0; ct < 8; ++ct) {
    int2 pp;
    pp.x = cvtpk(Oacc[ct][0] * rS, Oacc[ct][1] * rS);
    pp.y = cvtpk(Oacc[ct][2] * rS, Oacc[ct][3] * rS);
    *(int2*)&ot_s[nloc * 136 + 16 * ct + 4 * h] = pp;
  }
#pragma unroll
  for (int rep = 0; rep < 8; ++rep) {
    int idx = rep * 512 + tid;
    int o = idx >> 4, gp = idx & 15;
    int4 v = *(const int4*)&wo_bf[o * 128 + gp * 8];
    *(int4*)&wo_s[o * 128 + ((gp ^ (o & 7)) * 8)] = v;
  }
  __syncthreads();

  // ---- epilogue phase 2: out = gamma * (w_o @ O) + x
  // wave (oh, nq): o-half 128, n-quarter 32 (2 n-tiles)
  int nq = w & 3, oh = w >> 2;
  f32x4 acc[8][2];
#pragma unroll
  for (int j = 0; j < 8; ++j)
#pragma unroll
    for (int nn = 0; nn < 2; ++nn) acc[j][nn] = (f32x4){0.f, 0.f, 0.f, 0.f};

#pragma unroll
  for (int ks = 0; ks < 4; ++ks) {
    bf16x8 bfr0 = *(const bf16x8*)&ot_s[(32 * nq + q) * 136 + 32 * ks + 8 * h];
    bf16x8 bfr1 = *(const bf16x8*)&ot_s[(32 * nq + 16 + q) * 136 + 32 * ks + 8 * h];
#pragma unroll
    for (int j = 0; j < 8; ++j) {
      int o = 128 * oh + 16 * j + q;
      bf16x8 afr = *(const bf16x8*)&wo_s[o * 128 + (((4 * ks + h) ^ (o & 7)) * 8)];
      acc[j][0] = __builtin_amdgcn_mfma_f32_16x16x32_bf16(afr, bfr0, acc[j][0], 0, 0, 0);
      acc[j][1] = __builtin_amdgcn_mfma_f32_16x16x32_bf16(afr, bfr1, acc[j][1], 0, 0, 0);
    }
  }

#pragma unroll
  for (int j = 0; j < 8; ++j)
#pragma unroll
    for (int nn = 0; nn < 2; ++nn)
#pragma unroll
      for (int r = 0; r < 4; ++r) {
        int o = 128 * oh + 16 * j + 4 * h + r;
        int nn2 = n0 + 32 * nq + 16 * nn + q;
        size_t idx = ((size_t)b * C_ + o) * N_ + nn2;
        out[idx] = gm * acc[j][nn][r] + x[idx];
      }
}

extern "C" void kernel_launch(void* const* d_in, const int* in_sizes, int n_in,
                              void* d_out, int out_size, void* d_ws, size_t ws_size,
                              hipStream_t stream) {
  const float* x = (const float*)d_in[0];
  const float* wt = (const float*)d_in[1];
  const float* wp = (const float*)d_in[2];
  const float* wg = (const float*)d_in[3];
  const float* wo = (const float*)d_in[4];
  const float* gamma = (const float*)d_in[5];
  float* out = (float*)d_out;

  short* theta_t = (short*)d_ws;                       // 8*4096*32
  short* phi_t = theta_t + (size_t)B_ * N_ * CK;       // 8*1024*32
  short* g_bf = phi_t + (size_t)B_ * M_ * CK;          // 8*128*1024
  short* wcat = g_bf + (size_t)B_ * CG * M_;           // 192*256
  short* wo_bf = wcat + 192 * 256;                     // 256*128

  prep_kernel<<<dim3(80), 256, 0, stream>>>(wt, wp, wg, wo, wcat, wo_bf);
  proj_kernel<<<dim3(64, 8), 512, 0, stream>>>(x, wcat, theta_t, phi_t, g_bf);
  attn_out_kernel<<<dim3(256), 512, 0, stream>>>(theta_t, phi_t, g_bf, wo_bf, x, gamma, out);
}